// Round 1
// 459.938 us; speedup vs baseline: 1.0400x; 1.0400x over previous
//
#include <hip/hip_runtime.h>

static constexpr int MM  = 90000;  // cells
static constexpr int TT  = 150;    // steps
static constexpr int BS  = 256;    // threads per block (4 waves)
static constexpr int CPT = 4;      // cells per thread
static constexpr int CPB = BS * CPT;               // 1024 cells per block
static constexpr int NB  = (MM + CPB - 1) / CPB;   // 88 blocks
static constexpr int WPB = BS / 64;                // 4 waves per block
static constexpr int NWAVE  = NB * WPB;            // 352 waves total
static constexpr int WPAGES = 384;                 // 64 lanes x 6 loads (352 real + 32 sentinel)
static constexpr int PAGE_U32 = 2048;              // 8 KB page per wave -> own channel
static constexpr int PAGE_U64 = 1024;              // 8 KB page per block (halo words)

// Persistent device globals, re-initialized by init_ws_kernel EVERY launch.
// g_wmax: one channel-spread 8KB page PER WAVE; word [gw][t] = wave gw's |u|+c max
// at step t (nonzero by construction: c >= ~6e-4). Pages >= NWAVE preset to 1u
// (denormal 1.4e-45, neutral under fmax).
__device__ unsigned int       g_wmax[WPAGES][PAGE_U32];
__device__ unsigned long long g_edge_s[NB][PAGE_U64];   // [b][t*4 + side*2 + {AQ,F}]
__device__ unsigned long long g_dummy64;                // always nonzero (boundary filler)

__device__ __forceinline__ float softplus_f(float x) {
    return fmaxf(x, 0.0f) + log1pf(expf(-fabsf(x)));
}
__device__ __forceinline__ unsigned long long packAQ(float A, float Q) {
    return ((unsigned long long)__float_as_uint(Q) << 32) | (unsigned long long)__float_as_uint(A);
}
#define AG_LOAD32(p)     __hip_atomic_load((p), __ATOMIC_RELAXED, __HIP_MEMORY_SCOPE_AGENT)
#define AG_LOAD64(p)     __hip_atomic_load((p), __ATOMIC_RELAXED, __HIP_MEMORY_SCOPE_AGENT)
#define AG_STORE32(p, v) __hip_atomic_store((p), (v), __ATOMIC_RELAXED, __HIP_MEMORY_SCOPE_AGENT)
#define AG_STORE64(p, v) __hip_atomic_store((p), (v), __ATOMIC_RELAXED, __HIP_MEMORY_SCOPE_AGENT)

// 64-lane max reduce in 6 DPP stages (VALU-speed, no ds_bpermute).
// After the sequence lane 63 holds max of all 64 lanes. Values must be >= 0
// (bound_ctrl / masked lanes contribute 0.0f, neutral under fmax).
#define DPP_MAX(x, ctrl, rm, bm)                                                     \
    x = fmaxf(x, __int_as_float(__builtin_amdgcn_update_dpp(                          \
                     0, __float_as_int(x), (ctrl), (rm), (bm), true)))
__device__ __forceinline__ float wave_max64(float x) {
    DPP_MAX(x, 0x111, 0xf, 0xf);   // row_shr:1
    DPP_MAX(x, 0x112, 0xf, 0xf);   // row_shr:2
    DPP_MAX(x, 0x114, 0xf, 0xe);   // row_shr:4
    DPP_MAX(x, 0x118, 0xf, 0xc);   // row_shr:8
    DPP_MAX(x, 0x142, 0xa, 0xf);   // row_bcast:15
    DPP_MAX(x, 0x143, 0xc, 0xf);   // row_bcast:31 -> lane 63 = full max
    return x;
}

__global__ void init_ws_kernel() {
    int i = blockIdx.x * blockDim.x + threadIdx.x;
    int stride = gridDim.x * blockDim.x;
    unsigned int* pw = &g_wmax[0][0];
    for (int j = i; j < WPAGES * PAGE_U32; j += stride)
        pw[j] = ((j / PAGE_U32) < NWAVE) ? 0u : 1u;   // sentinel pages "already arrived"
    unsigned long long* pe = &g_edge_s[0][0];
    for (int j = i; j < NB * PAGE_U64; j += stride) pe[j] = 0ull;
    if (i == 0) g_dummy64 = ~0ull;
}

__global__ void __launch_bounds__(BS) sim_kernel(
    const float* __restrict__ Rs,
    const float* __restrict__ sim_dat,
    const float* __restrict__ sdc,
    const float* __restrict__ inflow,
    float* __restrict__ out)
{
    __shared__ float sE[2][WPB][2][3];   // [parity][wave][L/R edge cell][A,Q,F] (state_t)
    __shared__ float s_bc[2];            // [lam, w] uniform per step (wave0 computes)
    __shared__ float s_hL[3], s_hR[3];   // remote halo (A,Q,F)
    __shared__ float s_inflow[TT];

    const int b    = blockIdx.x;
    const int tid  = threadIdx.x;
    const int wv   = tid >> 6;
    const int lane = tid & 63;
    const int base = b * CPB + tid * CPT;   // 4 contiguous cells per thread
    const int gw   = b * WPB + wv;          // global wave id -> own wmax page

    for (int j = tid; j < TT; j += BS) s_inflow[j] = inflow[j];

    // ---- per-cell constants & initial state (registers all sim) ----
    float A[CPT], Q[CPT], A0v[CPT], bet[CPT], cbv[CPT], k2v[CPT], sq[CPT], FQ[CPT];
    bool  act[CPT];
    #pragma unroll
    for (int c = 0; c < CPT; ++c) {
        int i = base + c;
        act[c] = (i < MM);
        if (act[c]) {
            A[c]   = fmaxf(sim_dat[i], 1e-6f);
            Q[c]   = 0.1f * sim_dat[MM + i];
            A0v[c] = sdc[i] + 0.5f;
            bet[c] = sdc[MM + i] + 1.0f;
        } else { A[c] = 1.0f; Q[c] = 0.0f; A0v[c] = 1.0f; bet[c] = 1.0f; }
        cbv[c] = (0.5f * bet[c]) / 1060.0f;     // (0.5*beta)/RHO  (ref op order)
        k2v[c] = bet[c] / (3180.0f * A0v[c]);   // beta/(3*RHO*A0)
    }
    const bool isStart = (base == 0) | (base == 30000) | (base == 60000);                  // cell 0
    const bool isEnd   = (base + 3 == 29999) | (base + 3 == 59999) | (base + 3 == 89999);  // cell 3
    const int midSlot = (base == 15000) ? 0 : (base == 45000) ? 1 : (base == 75000) ? 2 : -1;
    float Rtot = 1.0f;
    if (isEnd) {
        int i3 = base + 3;
        float R1 = sdc[7 * MM + i3] + 0.5f;
        float R2 = sdc[8 * MM + i3] + 0.5f;
        if (i3 == 59999)      { R1 *= softplus_f(Rs[0]); R2 *= softplus_f(Rs[1]); }
        else if (i3 == 89999) { R1 *= softplus_f(Rs[2]); R2 *= softplus_f(Rs[3]); }
        Rtot = R1 + R2;
    }

    const bool pubL = (tid == 0) && (b > 0);            // publish my left edge (read by b-1)
    const bool pubR = (tid == BS - 1) && (b < NB - 1);  // publish my right edge (read by b+1)

    const unsigned int* pwl = &g_wmax[lane][0];         // wave0 poll base (lane-spread pages)

    // ---- initial derived state + t=0 publishes ----
    float s4 = 0.0f;
    #pragma unroll
    for (int c = 0; c < CPT; ++c) {
        sq[c] = sqrtf(A[c] / A0v[c]);
        float uu = Q[c] / A[c];
        float cc = sqrtf(cbv[c] * sq[c]);
        FQ[c] = Q[c] * uu + k2v[c] * A[c] * sq[c];
        s4 = fmaxf(s4, act[c] ? (fabsf(uu) + cc) : 0.0f);
    }
    if (pubL) {   // my L-edge words: [b][t*4+0]=AQ, [b][t*4+1]=F
        AG_STORE64(&g_edge_s[b][0], packAQ(A[0], Q[0]));
        AG_STORE64(&g_edge_s[b][1], (unsigned long long)__float_as_uint(FQ[0]));
    }
    if (pubR) {   // my R-edge words: [b][t*4+2]=AQ, [b][t*4+3]=F
        AG_STORE64(&g_edge_s[b][2], packAQ(A[3], Q[3]));
        AG_STORE64(&g_edge_s[b][3], (unsigned long long)__float_as_uint(FQ[3]));
    }
    {
        float red = wave_max64(s4);
        if (lane == 63) AG_STORE32(&g_wmax[gw][0], __float_as_uint(red));
    }
    if (lane == 0)       { sE[0][wv][0][0] = A[0]; sE[0][wv][0][1] = Q[0]; sE[0][wv][0][2] = FQ[0]; }
    else if (lane == 63) { sE[0][wv][1][0] = A[3]; sE[0][wv][1][1] = Q[3]; sE[0][wv][1][2] = FQ[3]; }
    // no pre-loop barrier needed: first in-loop __syncthreads orders sE/s_inflow.

    for (int t = 0; t < TT; ++t) {
        const int par = t & 1, npar = par ^ 1;

        // ===== wave0: issue FIRST poll sample before the overlap compute =====
        unsigned int x0, x1, x2, x3, x4, x5;
        unsigned long long e64;
        const unsigned long long* pE = &g_dummy64;
        if (wv == 0) {
            const int t4 = t * 4;
            if (lane == 0 && b > 0)           pE = &g_edge_s[b - 1][t4 + 2];  // left nbr R-AQ
            else if (lane == 1 && b > 0)      pE = &g_edge_s[b - 1][t4 + 3];  // left nbr R-F
            else if (lane == 2 && b < NB - 1) pE = &g_edge_s[b + 1][t4 + 0];  // right nbr L-AQ
            else if (lane == 3 && b < NB - 1) pE = &g_edge_s[b + 1][t4 + 1];  // right nbr L-F
            const unsigned int* p = pwl + t;
            x0 = AG_LOAD32(p);
            x1 = AG_LOAD32(p +  64 * PAGE_U32);
            x2 = AG_LOAD32(p + 128 * PAGE_U32);
            x3 = AG_LOAD32(p + 192 * PAGE_U32);
            x4 = AG_LOAD32(p + 256 * PAGE_U32);
            x5 = AG_LOAD32(p + 320 * PAGE_U32);
            e64 = AG_LOAD64(pE);
        }

        // ===== overlap phase (all waves): register-only neighbor exchange =====
        float Am = __shfl_up(A[3], 1, 64),  Qm = __shfl_up(Q[3], 1, 64),  Fm = __shfl_up(FQ[3], 1, 64);
        float Ap = __shfl_down(A[0], 1, 64), Qp = __shfl_down(Q[0], 1, 64), Fp = __shfl_down(FQ[0], 1, 64);

        float dFA[CPT], lapA[CPT], dFQ[CPT], lapQ[CPT];
        #pragma unroll
        for (int c = 0; c < CPT; ++c) {
            float Al = (c == 0) ? Am : A[c-1],  Ql = (c == 0) ? Qm : Q[c-1],  Fl = (c == 0) ? Fm : FQ[c-1];
            float Ar = (c == 3) ? Ap : A[c+1],  Qr = (c == 3) ? Qp : Q[c+1],  Fr = (c == 3) ? Fp : FQ[c+1];
            dFA[c]  = 0.5f * (Qr - Ql);
            lapA[c] = 0.5f * (Ar - 2.0f * A[c] + Al);
            dFQ[c]  = 0.5f * (Fr - Fl);
            lapQ[c] = 0.5f * (Qr - 2.0f * Q[c] + Ql);
        }
        if (midSlot >= 0) out[t * 3 + midSlot] = bet[0] * (sq[0] - 1.0f);
        // BC values depend only on step-t state: compute (incl. divide) pre-barrier
        float qFix = 0.0f;
        if (isStart) qFix = s_inflow[t];
        if (isEnd)   qFix = (bet[3] * (sq[3] - 1.0f)) / Rtot;

        // ===== wave0: finish spin; DPP-reduce; uniform dt/lam/w in barrier shadow =====
        if (wv == 0) {
            const unsigned int* p = pwl + t;
            bool ok = __all((x0 != 0u) & (x1 != 0u) & (x2 != 0u) & (x3 != 0u) &
                            (x4 != 0u) & (x5 != 0u) & (e64 != 0ull));
            while (!ok) {
                x0 = AG_LOAD32(p);
                x1 = AG_LOAD32(p +  64 * PAGE_U32);
                x2 = AG_LOAD32(p + 128 * PAGE_U32);
                x3 = AG_LOAD32(p + 192 * PAGE_U32);
                x4 = AG_LOAD32(p + 256 * PAGE_U32);
                x5 = AG_LOAD32(p + 320 * PAGE_U32);
                e64 = AG_LOAD64(pE);
                ok = __all((x0 != 0u) & (x1 != 0u) & (x2 != 0u) & (x3 != 0u) &
                           (x4 != 0u) & (x5 != 0u) & (e64 != 0ull));
            }
            // halo hand-off first (independent of the reduce)
            if (lane == 0 && b > 0)           { s_hL[0] = __uint_as_float((unsigned int)e64);
                                                s_hL[1] = __uint_as_float((unsigned int)(e64 >> 32)); }
            else if (lane == 1 && b > 0)      { s_hL[2] = __uint_as_float((unsigned int)e64); }
            else if (lane == 2 && b < NB - 1) { s_hR[0] = __uint_as_float((unsigned int)e64);
                                                s_hR[1] = __uint_as_float((unsigned int)(e64 >> 32)); }
            else if (lane == 3 && b < NB - 1) { s_hR[2] = __uint_as_float((unsigned int)e64); }
            float m = fmaxf(fmaxf(fmaxf(__uint_as_float(x0), __uint_as_float(x1)),
                                  fmaxf(__uint_as_float(x2), __uint_as_float(x3))),
                            fmaxf(__uint_as_float(x4), __uint_as_float(x5)));
            m = wave_max64(m);
            const float smax = __int_as_float(__builtin_amdgcn_readlane(__float_as_int(m), 63));
            const float dt  = ((float)(0.9 * 0.001)) / smax;   // ref op order
            const float lam = dt / 0.001f;
            const float w   = lam * smax;
            if (lane == 0) { s_bc[0] = lam; s_bc[1] = w; }
        }
        __syncthreads();   // the ONLY barrier per step
        const float lam = s_bc[0];
        const float w   = s_bc[1];

        // ===== per-wave edge fixes: lane 0 / lane 63 stencil terms from sE / remote halo =====
        if (lane == 0 && (wv > 0 || b > 0)) {
            float Al, Ql, Fl;
            if (wv > 0) { Al = sE[par][wv-1][1][0]; Ql = sE[par][wv-1][1][1]; Fl = sE[par][wv-1][1][2]; }
            else        { Al = s_hL[0];             Ql = s_hL[1];             Fl = s_hL[2]; }
            dFA[0]  = 0.5f * (Q[1] - Ql);
            lapA[0] = 0.5f * (A[1] - 2.0f * A[0] + Al);
            dFQ[0]  = 0.5f * (FQ[1] - Fl);
            lapQ[0] = 0.5f * (Q[1] - 2.0f * Q[0] + Ql);
        }
        if (lane == 63 && (wv < WPB - 1 || b < NB - 1)) {
            float Ar, Qr, Fr;
            if (wv < WPB - 1) { Ar = sE[par][wv+1][0][0]; Qr = sE[par][wv+1][0][1]; Fr = sE[par][wv+1][0][2]; }
            else              { Ar = s_hR[0];             Qr = s_hR[1];             Fr = s_hR[2]; }
            dFA[3]  = 0.5f * (Qr - Q[2]);
            lapA[3] = 0.5f * (Ar - 2.0f * A[3] + A[2]);
            dFQ[3]  = 0.5f * (Fr - FQ[2]);
            lapQ[3] = 0.5f * (Qr - 2.0f * Q[3] + Q[2]);
        }

        // ===== update + BCs + clamp =====
        #pragma unroll
        for (int c = 0; c < CPT; ++c) {
            int i = base + c;
            if (act[c] && i > 0 && i < MM - 1) {
                A[c] = fmaf(w, lapA[c], fmaf(-lam, dFA[c], A[c]));
                Q[c] = fmaf(w, lapQ[c], fmaf(-lam, dFQ[c], Q[c]));
            }
        }
        if (isStart) Q[0] = qFix;
        if (isEnd)   Q[3] = qFix;
        #pragma unroll
        for (int c = 0; c < CPT; ++c) A[c] = fmaxf(A[c], 1e-6f);

        // publish t+1 edge AQ ASAP
        const int n4 = (t + 1) * 4;
        if (pubL) AG_STORE64(&g_edge_s[b][n4 + 0], packAQ(A[0], Q[0]));
        if (pubR) AG_STORE64(&g_edge_s[b][n4 + 2], packAQ(A[3], Q[3]));

        // ===== derived state: s4 path first (it gates every other block), FQ after =====
        float uu[CPT];
        s4 = 0.0f;
        #pragma unroll
        for (int c = 0; c < CPT; ++c) {
            sq[c] = sqrtf(A[c] / A0v[c]);
            uu[c] = Q[c] / A[c];
            float cc = sqrtf(cbv[c] * sq[c]);
            s4 = fmaxf(s4, act[c] ? (fabsf(uu[c]) + cc) : 0.0f);
        }
        {
            float red = wave_max64(s4);
            if (lane == 63) AG_STORE32(&g_wmax[gw][t + 1], __float_as_uint(red));  // per-wave direct publish
        }
        #pragma unroll
        for (int c = 0; c < CPT; ++c)
            FQ[c] = Q[c] * uu[c] + k2v[c] * A[c] * sq[c];

        if (pubL) AG_STORE64(&g_edge_s[b][n4 + 1], (unsigned long long)__float_as_uint(FQ[0]));
        if (pubR) AG_STORE64(&g_edge_s[b][n4 + 3], (unsigned long long)__float_as_uint(FQ[3]));

        // intra-block wave-edge state for t+1 (ordered vs readers by next step's barrier:
        // spin(t+1) can only pass after every wave published wmax[t+1], which happens
        // after these writes -> full round-trip ordering, no second __syncthreads needed)
        if (lane == 0)       { sE[npar][wv][0][0] = A[0]; sE[npar][wv][0][1] = Q[0]; sE[npar][wv][0][2] = FQ[0]; }
        else if (lane == 63) { sE[npar][wv][1][0] = A[3]; sE[npar][wv][1][1] = Q[3]; sE[npar][wv][1][2] = FQ[3]; }
    }
}

extern "C" void kernel_launch(void* const* d_in, const int* in_sizes, int n_in,
                              void* d_out, int out_size, void* d_ws, size_t ws_size,
                              hipStream_t stream) {
    (void)in_sizes; (void)n_in; (void)d_ws; (void)ws_size; (void)out_size;

    const float* Rs      = (const float*)d_in[0];
    const float* sim_dat = (const float*)d_in[1];
    const float* sdc     = (const float*)d_in[2];
    const float* inflow  = (const float*)d_in[3];
    float* out = (float*)d_out;

    hipLaunchKernelGGL(init_ws_kernel, dim3(240), dim3(256), 0, stream);

    // 88 blocks x 4 waves, ~1 KB LDS -> trivially co-resident on 256 CUs.
    hipLaunchKernelGGL(sim_kernel, dim3(NB), dim3(BS), 0, stream,
                       Rs, sim_dat, sdc, inflow, out);
}